// Round 1
// baseline (30.913 us; speedup 1.0000x reference)
//
#include <hip/hip_runtime.h>

// Workspace float layout (total 8080 floats = 32320 bytes):
#define NF_W1P  0      // 32  W1 block partial sums
#define NF_W2P  32     // 96  W2 block partial sums
#define NF_B1   128    // 1   sum(b1)
#define NF_B2   129    // 1   sum(b2)
#define NF_S0   130    // 512 s0[b*64+l] = sum_d z1[b,l,d]
#define NF_CW3P 656    // 8*768 W3 column-sum partials (8 row-groups of 96)
#define NF_CW3  6800   // 768 colsum(W3)
#define NF_U    7568   // 512 u[b*64+l]

__device__ __forceinline__ float wave_reduce(float v) {
#pragma unroll
    for (int off = 32; off; off >>= 1) v += __shfl_down(v, off, 64);
    return v;
}

__device__ __forceinline__ float block_reduce_256(float v) {
    __shared__ float sm[4];
    v = wave_reduce(v);
    int lane = threadIdx.x & 63, wid = threadIdx.x >> 6;
    if (lane == 0) sm[wid] = v;
    __syncthreads();
    if (threadIdx.x == 0) v = sm[0] + sm[1] + sm[2] + sm[3];
    return v;
}

// 282 blocks x 256 threads. Fixed partition -> deterministic summation order.
__global__ __launch_bounds__(256) void k_reduce(
    const float* __restrict__ z1, const float* __restrict__ W1,
    const float* __restrict__ b1, const float* __restrict__ W2,
    const float* __restrict__ b2, const float* __restrict__ W3,
    float* __restrict__ f) {
    const int blk = blockIdx.x, tid = threadIdx.x;
    if (blk < 128) {
        // blocks 0..31: W1 (32 x 4096), blocks 32..127: W2 (96 x 4096)
        const float* p = (blk < 32) ? (W1 + blk * 4096) : (W2 + (blk - 32) * 4096);
        float s = 0.f;
#pragma unroll
        for (int i = 0; i < 16; ++i) s += p[tid + i * 256];
        s = block_reduce_256(s);
        if (tid == 0) f[blk] = s;                      // f[0..127]
    } else if (blk == 128) {
        float s = b1[tid] + b1[tid + 256];             // 512 elems
        s = block_reduce_256(s);
        if (tid == 0) f[NF_B1] = s;
    } else if (blk == 129) {
        float s = b2[tid] + b2[tid + 256] + b2[tid + 512]; // 768 elems
        s = block_reduce_256(s);
        if (tid == 0) f[NF_B2] = s;
    } else if (blk < 258) {
        // s0: one wave per (b,l) row, 4 rows/block, blocks 130..257 -> 512 rows
        const int lane = tid & 63, wid = tid >> 6;
        const int row = (blk - 130) * 4 + wid;         // 0..511
        const float* p = z1 + row * 256;
        float s = p[lane] + p[lane + 64] + p[lane + 128] + p[lane + 192];
        s = wave_reduce(s);
        if (lane == 0) f[NF_S0 + row] = s;
    } else {
        // W3 column-sum partials: 24 blocks = 3 col-groups x 8 row-groups of 96
        const int g = blk - 258;                       // 0..23
        const int cg = g % 3, rg = g / 3;
        const int e = cg * 256 + tid;                  // 0..767
        const float* p = W3 + rg * 96 * 768 + e;
        float s = 0.f;
#pragma unroll 8
        for (int d = 0; d < 96; ++d) s += p[d * 768];
        f[NF_CW3P + rg * 768 + e] = s;
    }
}

// 1 block x 768 threads: fold partials into cw3[768] and u[512].
__global__ __launch_bounds__(768) void k_combine(float* __restrict__ f) {
    const int tid = threadIdx.x;
    float c = 0.f;
#pragma unroll
    for (int r = 0; r < 8; ++r) c += f[NF_CW3P + r * 768 + tid];
    f[NF_CW3 + tid] = c;
    if (tid < 512) {
        float S1 = 0.f, S2 = 0.f;
        for (int i = 0; i < 32; ++i) S1 += f[NF_W1P + i];
        for (int i = 0; i < 96; ++i) S2 += f[NF_W2P + i];
        // c0 = 256^2 * s0 (exact: power-of-two scale)
        const float u = (65536.0f * f[NF_S0 + tid] * S1 + f[NF_B1]) * S2 + f[NF_B2];
        f[NF_U + tid] = u;
    }
}

// out[b,t,e] = u[b, t>>6] * cw3[e] + b3[e].  One wave per 768-float row,
// 4 rows/block, 3 float4 stores per lane. 8192 blocks cover 32768 rows.
__global__ __launch_bounds__(256) void k_write(
    const float* __restrict__ f, const float* __restrict__ b3,
    float* __restrict__ out) {
    const int tid = threadIdx.x;
    const int lane = tid & 63, wid = tid >> 6;
    const int row = blockIdx.x * 4 + wid;              // 0..32767
    // row>>6 is uniform across the block (4 rows never straddle a 64-row group)
    const float u = f[NF_U + (blockIdx.x >> 4)];
    const float4* __restrict__ cw4 = (const float4*)(f + NF_CW3);
    const float4* __restrict__ b4  = (const float4*)b3;
    float4* __restrict__ o = (float4*)(out + (size_t)row * 768);
#pragma unroll
    for (int k = 0; k < 3; ++k) {
        const int e4 = lane + k * 64;
        const float4 c = cw4[e4];
        const float4 b = b4[e4];
        float4 r;
        r.x = fmaf(u, c.x, b.x);
        r.y = fmaf(u, c.y, b.y);
        r.z = fmaf(u, c.z, b.z);
        r.w = fmaf(u, c.w, b.w);
        o[e4] = r;
    }
}

extern "C" void kernel_launch(void* const* d_in, const int* in_sizes, int n_in,
                              void* d_out, int out_size, void* d_ws, size_t ws_size,
                              hipStream_t stream) {
    const float* z1 = (const float*)d_in[0];
    const float* W1 = (const float*)d_in[1];
    const float* b1 = (const float*)d_in[2];
    const float* W2 = (const float*)d_in[3];
    const float* b2 = (const float*)d_in[4];
    const float* W3 = (const float*)d_in[5];
    const float* b3 = (const float*)d_in[6];
    float* out = (float*)d_out;
    float* f = (float*)d_ws;   // needs 32320 bytes

    k_reduce<<<282, 256, 0, stream>>>(z1, W1, b1, W2, b2, W3, f);
    k_combine<<<1, 768, 0, stream>>>(f);
    k_write<<<8192, 256, 0, stream>>>(f, b3, out);
}

// Round 2
// 28.511 us; speedup vs baseline: 1.0843x; 1.0843x over previous
//
#include <hip/hip_runtime.h>

typedef float f4 __attribute__((ext_vector_type(4)));

// Workspace float layout:
#define NF_W1P  0      // 32  W1 block partial sums
#define NF_W2P  32     // 96  W2 block partial sums
#define NF_B1   128    // 1   sum(b1)
#define NF_B2   129    // 1   sum(b2)
#define NF_S0   130    // 512 s0[b*64+l] = sum_d z1[b,l,d]
#define NF_CW3P 656    // 8*768 W3 column-sum partials (8 row-groups of 96)

__device__ __forceinline__ float wave_reduce(float v) {
#pragma unroll
    for (int off = 32; off; off >>= 1) v += __shfl_down(v, off, 64);
    return v;
}

__device__ __forceinline__ float block_reduce_256(float v) {
    __shared__ float sm[4];
    v = wave_reduce(v);
    int lane = threadIdx.x & 63, wid = threadIdx.x >> 6;
    if (lane == 0) sm[wid] = v;
    __syncthreads();
    if (threadIdx.x == 0) v = sm[0] + sm[1] + sm[2] + sm[3];
    return v;
}

// 282 blocks x 256 threads. Fixed partition -> deterministic summation order.
__global__ __launch_bounds__(256) void k_reduce(
    const float* __restrict__ z1, const float* __restrict__ W1,
    const float* __restrict__ b1, const float* __restrict__ W2,
    const float* __restrict__ b2, const float* __restrict__ W3,
    float* __restrict__ f) {
    const int blk = blockIdx.x, tid = threadIdx.x;
    if (blk < 128) {
        // blocks 0..31: W1 (32 x 4096), blocks 32..127: W2 (96 x 4096)
        const float* p = (blk < 32) ? (W1 + blk * 4096) : (W2 + (blk - 32) * 4096);
        float s = 0.f;
#pragma unroll
        for (int i = 0; i < 16; ++i) s += p[tid + i * 256];
        s = block_reduce_256(s);
        if (tid == 0) f[blk] = s;                      // f[0..127]
    } else if (blk == 128) {
        float s = b1[tid] + b1[tid + 256];             // 512 elems
        s = block_reduce_256(s);
        if (tid == 0) f[NF_B1] = s;
    } else if (blk == 129) {
        float s = b2[tid] + b2[tid + 256] + b2[tid + 512]; // 768 elems
        s = block_reduce_256(s);
        if (tid == 0) f[NF_B2] = s;
    } else if (blk < 258) {
        // s0: one wave per (b,l) row, 4 rows/block, blocks 130..257 -> 512 rows
        const int lane = tid & 63, wid = tid >> 6;
        const int row = (blk - 130) * 4 + wid;         // 0..511
        const float* p = z1 + row * 256;
        float s = p[lane] + p[lane + 64] + p[lane + 128] + p[lane + 192];
        s = wave_reduce(s);
        if (lane == 0) f[NF_S0 + row] = s;
    } else {
        // W3 column-sum partials: 24 blocks = 3 col-groups x 8 row-groups of 96
        const int g = blk - 258;                       // 0..23
        const int cg = g % 3, rg = g / 3;
        const int e = cg * 256 + tid;                  // 0..767
        const float* p = W3 + rg * 96 * 768 + e;
        float s = 0.f;
#pragma unroll 8
        for (int d = 0; d < 96; ++d) s += p[d * 768];
        f[NF_CW3P + rg * 768 + e] = s;
    }
}

// out[b,t,e] = u[b, t>>6] * cw3[e] + b3[e].
// Grid 2048 x 256: each block folds partials into shared (prologue), then
// writes 16 rows (4 rows/wave, 3 float4 stores/lane/row).
__global__ __launch_bounds__(256) void k_write(
    const float* __restrict__ f, const float* __restrict__ b3,
    float* __restrict__ out) {
    __shared__ float cw_sm[768];
    __shared__ float b_sm[768];
    __shared__ float u_sm;
    const int tid = threadIdx.x;

    // Fold the 8 row-group partials of cw3; stage b3. Same order every block
    // -> deterministic and identical across blocks.
#pragma unroll
    for (int k = 0; k < 3; ++k) {
        const int e = tid + k * 256;
        float c = 0.f;
#pragma unroll
        for (int r = 0; r < 8; ++r) c += f[NF_CW3P + r * 768 + e];
        cw_sm[e] = c;
        b_sm[e] = b3[e];
    }
    // Wave 0: S1 (32 partials), S2 (96 partials), then u for this block.
    if (tid < 64) {
        float a = (tid < 32) ? f[NF_W1P + tid] : 0.f;
        float b = f[NF_W2P + tid] + ((tid < 32) ? f[NF_W2P + 64 + tid] : 0.f);
#pragma unroll
        for (int off = 32; off; off >>= 1) {
            a += __shfl_down(a, off, 64);
            b += __shfl_down(b, off, 64);
        }
        if (tid == 0) {
            const int uidx = blockIdx.x >> 2;   // rows b*16..b*16+15 share t>>6
            u_sm = (65536.0f * f[NF_S0 + uidx] * a + f[NF_B1]) * b + f[NF_B2];
        }
    }
    __syncthreads();

    const float u = u_sm;
    const int lane = tid & 63, wid = tid >> 6;
    const f4* __restrict__ cw4 = (const f4*)cw_sm;
    const f4* __restrict__ b4  = (const f4*)b_sm;
#pragma unroll
    for (int r = 0; r < 4; ++r) {
        const int row = blockIdx.x * 16 + wid * 4 + r;
        f4* o = (f4*)(out + (size_t)row * 768);
#pragma unroll
        for (int k = 0; k < 3; ++k) {
            const int e4 = lane + k * 64;
            const f4 c = cw4[e4];
            const f4 b = b4[e4];
            f4 v;
            v.x = fmaf(u, c.x, b.x);
            v.y = fmaf(u, c.y, b.y);
            v.z = fmaf(u, c.z, b.z);
            v.w = fmaf(u, c.w, b.w);
            __builtin_nontemporal_store(v, &o[e4]);
        }
    }
}

extern "C" void kernel_launch(void* const* d_in, const int* in_sizes, int n_in,
                              void* d_out, int out_size, void* d_ws, size_t ws_size,
                              hipStream_t stream) {
    const float* z1 = (const float*)d_in[0];
    const float* W1 = (const float*)d_in[1];
    const float* b1 = (const float*)d_in[2];
    const float* W2 = (const float*)d_in[3];
    const float* b2 = (const float*)d_in[4];
    const float* W3 = (const float*)d_in[5];
    const float* b3 = (const float*)d_in[6];
    float* out = (float*)d_out;
    float* f = (float*)d_ws;   // needs 28 KB

    k_reduce<<<282, 256, 0, stream>>>(z1, W1, b1, W2, b2, W3, f);
    k_write<<<2048, 256, 0, stream>>>(f, b3, out);
}